// Round 1
// baseline (644.833 us; speedup 1.0000x reference)
//
#include <hip/hip_runtime.h>
#include <hip/hip_bf16.h>
#include <stddef.h>

typedef __attribute__((ext_vector_type(8))) short short8;
typedef __attribute__((ext_vector_type(4))) short short4v;
typedef __attribute__((ext_vector_type(4))) float floatx4;

#define N_ 4
#define C_ 256
#define H_ 128
#define W_ 128
#define HW_ (H_*W_)
#define CD_ 64     // C/4
#define E_ 36      // k2*up2
#define OC_ 256

// round-to-nearest-even f32 -> bf16 bits
static __device__ __forceinline__ unsigned short f2bf(float f) {
    union { float f; unsigned u; } v; v.f = f;
    unsigned r = v.u + 0x7fff + ((v.u >> 16) & 1);
    return (unsigned short)(r >> 16);
}

// ---------------- Kernel 1: 1x1 down conv (f32) ----------------
// grid 256 = n(4) * ogrp(2) * chunk(32); 256 thr, 2 px/thread
__global__ __launch_bounds__(256) void k_down(
    const float* __restrict__ x, const float* __restrict__ wd,
    const float* __restrict__ bd, float* __restrict__ t)
{
    int bx = blockIdx.x;
    int n = bx >> 6;
    int og = (bx >> 5) & 1;
    int chunk = bx & 31;
    int px0 = chunk * 512 + threadIdx.x * 2;
    const float* xb = x + (size_t)n * C_ * HW_ + px0;
    const float* wb = wd + og * 32 * C_;
    float acc0[32], acc1[32];
    #pragma unroll
    for (int o = 0; o < 32; o++) { acc0[o] = 0.f; acc1[o] = 0.f; }
    for (int c8 = 0; c8 < C_; c8 += 8) {
        float2 xv[8];
        #pragma unroll
        for (int cc = 0; cc < 8; cc++)
            xv[cc] = *(const float2*)(xb + (size_t)(c8 + cc) * HW_);
        #pragma unroll
        for (int o = 0; o < 32; o++) {
            #pragma unroll
            for (int cc = 0; cc < 8; cc++) {
                float w = wb[o * C_ + c8 + cc];   // uniform -> s_load
                acc0[o] = fmaf(w, xv[cc].x, acc0[o]);
                acc1[o] = fmaf(w, xv[cc].y, acc1[o]);
            }
        }
    }
    float* tb = t + ((size_t)n * CD_ + og * 32) * HW_ + px0;
    #pragma unroll
    for (int o = 0; o < 32; o++) {
        float b = bd[og * 32 + o];
        float2 r; r.x = acc0[o] + b; r.y = acc1[o] + b;
        *(float2*)(tb + (size_t)o * HW_) = r;
    }
}

// ---------------- Kernel 2: 3x3 enc conv + softmax (f32) ----------------
// grid 256, 256 thr, 1 px/thread
__global__ __launch_bounds__(256) void k_enc(
    const float* __restrict__ t, const float* __restrict__ we,
    const float* __restrict__ be, float* __restrict__ kern)
{
    int px = blockIdx.x * 256 + threadIdx.x;   // 0..65535
    int n = px >> 14;
    int hw = px & (HW_ - 1);
    int h = hw >> 7, w = hw & (W_ - 1);
    float acc[E_];
    #pragma unroll
    for (int e = 0; e < E_; e++) acc[e] = be[e];
    const float* tb = t + (size_t)n * CD_ * HW_;
    bool hv[3], wv[3];
    int ho[3], wo[3];
    #pragma unroll
    for (int d = 0; d < 3; d++) {
        int hh = h + d - 1; hv[d] = (hh >= 0 && hh < H_); ho[d] = hh * W_;
        int ww = w + d - 1; wv[d] = (ww >= 0 && ww < W_); wo[d] = ww;
    }
    for (int c = 0; c < CD_; c++) {
        float tv[9];
        #pragma unroll
        for (int di = 0; di < 3; di++)
            #pragma unroll
            for (int dj = 0; dj < 3; dj++)
                tv[di * 3 + dj] = (hv[di] && wv[dj]) ? tb[c * HW_ + ho[di] + wo[dj]] : 0.f;
        #pragma unroll
        for (int e = 0; e < E_; e++) {
            const float* wp = we + (size_t)(e * CD_ + c) * 9;  // uniform -> s_load
            float a = acc[e];
            #pragma unroll
            for (int ij = 0; ij < 9; ij++) a = fmaf(tv[ij], wp[ij], a);
            acc[e] = a;
        }
    }
    // softmax over k (stride 4) for each q; channel layout e = k*4 + q
    float out[E_];
    #pragma unroll
    for (int q = 0; q < 4; q++) {
        float m = acc[q];
        #pragma unroll
        for (int k = 1; k < 9; k++) m = fmaxf(m, acc[k * 4 + q]);
        float ex[9]; float s = 0.f;
        #pragma unroll
        for (int k = 0; k < 9; k++) { ex[k] = __expf(acc[k * 4 + q] - m); s += ex[k]; }
        float inv = 1.f / s;
        #pragma unroll
        for (int k = 0; k < 9; k++) out[k * 4 + q] = ex[k] * inv;
    }
    float4* kp4 = (float4*)(kern + (size_t)px * E_);
    #pragma unroll
    for (int i = 0; i < 9; i++)
        kp4[i] = make_float4(out[i * 4], out[i * 4 + 1], out[i * 4 + 2], out[i * 4 + 3]);
}

// ---------------- Kernel 3: fused reassembly + pixel shuffle + 1x1 conv (MFMA) ----------------
// grid 2048 = n(4) * ty(32) * tx(16); 512 thr = 8 waves (2M x 4N)
// block tile: 256 out-ch x 128 cols (32 px * 4 q); K=256 in chunks of 32
#define TW_ 8
#define TH_ 4
__global__ __launch_bounds__(512) void k_main(
    const float* __restrict__ x, const float* __restrict__ kern,
    const float* __restrict__ wo, const float* __restrict__ bo,
    float* __restrict__ y)
{
    __shared__ short Asm[256 * 40];   // w_out chunk bf16, stride 40 (16B-aligned rows)
    __shared__ short Bsm[128 * 40];   // reassembled cols bf16, [col][cc]
    __shared__ float Xsm[32 * 60];    // x halo tile [c][6][10]
    __shared__ float Ksm[32 * 37];    // kern weights [p][36] (+1 pad)
    __shared__ float bsm[256];

    int tid = threadIdx.x;
    int bx = blockIdx.x;
    int n = bx >> 9;
    int rem = bx & 511;
    int ty = rem >> 4, tx = rem & 15;
    int h0 = ty * TH_, w0 = tx * TW_;

    int lane = tid & 63;
    int wave = tid >> 6;
    int wm = wave >> 2, wn = wave & 3;

    if (tid < 256) bsm[tid] = bo[tid];
    for (int idx = tid; idx < 32 * E_; idx += 512) {
        int p = idx / E_, e = idx - p * E_;
        int py = p >> 3, pxl = p & 7;
        Ksm[p * 37 + e] = kern[((size_t)((n * H_ + h0 + py) * W_) + w0 + pxl) * E_ + e];
    }

    floatx4 acc[8][2];
    #pragma unroll
    for (int fm = 0; fm < 8; fm++)
        #pragma unroll
        for (int fn = 0; fn < 2; fn++)
            acc[fm][fn] = (floatx4)0.f;

    for (int c0 = 0; c0 < C_; c0 += 32) {
        // stage A chunk: w_out[o][c0..c0+31] -> bf16 LDS
        {
            int o = tid >> 1, part = tid & 1;
            const float* wr = wo + (size_t)o * C_ + c0 + part * 16;
            short* ap = &Asm[o * 40 + part * 16];
            #pragma unroll
            for (int i = 0; i < 4; i++) {
                float4 v = *(const float4*)(wr + i * 4);
                short4v s;
                s.x = (short)f2bf(v.x); s.y = (short)f2bf(v.y);
                s.z = (short)f2bf(v.z); s.w = (short)f2bf(v.w);
                *(short4v*)(ap + i * 4) = s;
            }
        }
        // stage x halo tile (zero padded)
        for (int idx = tid; idx < 1920; idx += 512) {
            int c = idx / 60;
            int r = idx - c * 60;
            int hh = r / 10, ww = r - hh * 10;
            int gh = h0 + hh - 1, gw = w0 + ww - 1;
            float v = 0.f;
            if (gh >= 0 && gh < H_ && gw >= 0 && gw < W_)
                v = x[(((size_t)n * C_ + c0 + c) * H_ + gh) * W_ + gw];
            Xsm[idx] = v;
        }
        __syncthreads();
        // build B: v[c][p][q] = sum_k x_patch * kern
        {
            int p = tid & 31, q = (tid >> 5) & 3, cg = tid >> 7;
            int py = p >> 3, pxl = p & 7;
            const float* kp = &Ksm[p * 37];
            float kv[9];
            #pragma unroll
            for (int k = 0; k < 9; k++) kv[k] = kp[k * 4 + q];
            short8 vout;
            #pragma unroll
            for (int ci = 0; ci < 8; ci++) {
                const float* xp = &Xsm[(cg * 8 + ci) * 60 + py * 10 + pxl];
                float v = 0.f;
                #pragma unroll
                for (int di = 0; di < 3; di++)
                    #pragma unroll
                    for (int dj = 0; dj < 3; dj++)
                        v = fmaf(xp[di * 10 + dj], kv[di * 3 + dj], v);
                vout[ci] = (short)f2bf(v);
            }
            int col = p * 4 + q;
            *(short8*)&Bsm[col * 40 + cg * 8] = vout;
        }
        __syncthreads();
        // MFMA: wave tile 128Mx32N -> 8x2 frags of 16x16, K=32 per chunk
        {
            short8 bfrag[2];
            #pragma unroll
            for (int fn = 0; fn < 2; fn++) {
                int col = wn * 32 + fn * 16 + (lane & 15);
                bfrag[fn] = *(const short8*)&Bsm[col * 40 + (lane >> 4) * 8];
            }
            #pragma unroll
            for (int fm = 0; fm < 8; fm++) {
                int row = wm * 128 + fm * 16 + (lane & 15);
                short8 afrag = *(const short8*)&Asm[row * 40 + (lane >> 4) * 8];
                acc[fm][0] = __builtin_amdgcn_mfma_f32_16x16x32_bf16(afrag, bfrag[0], acc[fm][0], 0, 0, 0);
                acc[fm][1] = __builtin_amdgcn_mfma_f32_16x16x32_bf16(afrag, bfrag[1], acc[fm][1], 0, 0, 0);
            }
        }
        __syncthreads();
    }
    // epilogue: D layout row=(lane>>4)*4+i, col=lane&15; pixel shuffle + bias
    #pragma unroll
    for (int fm = 0; fm < 8; fm++) {
        int o0 = wm * 128 + fm * 16 + ((lane >> 4) << 2);
        #pragma unroll
        for (int fn = 0; fn < 2; fn++) {
            int col = wn * 32 + fn * 16 + (lane & 15);
            int p = col >> 2, q = col & 3;
            int py = p >> 3, pxl = p & 7;
            int h2 = ((h0 + py) << 1) + (q >> 1);
            int w2 = ((w0 + pxl) << 1) + (q & 1);
            float* yp = y + (size_t)n * OC_ * 65536 + (size_t)h2 * 256 + w2;
            #pragma unroll
            for (int i = 0; i < 4; i++) {
                int oo = o0 + i;
                yp[(size_t)oo * 65536] = acc[fm][fn][i] + bsm[oo];
            }
        }
    }
}

extern "C" void kernel_launch(void* const* d_in, const int* in_sizes, int n_in,
                              void* d_out, int out_size, void* d_ws, size_t ws_size,
                              hipStream_t stream) {
    const float* x  = (const float*)d_in[0];
    const float* wd = (const float*)d_in[1];
    const float* bd = (const float*)d_in[2];
    const float* we = (const float*)d_in[3];
    const float* be = (const float*)d_in[4];
    const float* wo = (const float*)d_in[5];
    const float* bo = (const float*)d_in[6];
    float* y = (float*)d_out;

    float* t    = (float*)d_ws;                      // [4][64][16384] f32 = 16.8 MB
    float* kern = t + (size_t)N_ * CD_ * HW_;        // [65536][36] f32  =  9.4 MB

    k_down<<<256, 256, 0, stream>>>(x, wd, bd, t);
    k_enc <<<256, 256, 0, stream>>>(t, we, be, kern);
    k_main<<<2048, 512, 0, stream>>>(x, kern, wo, bo, y);
}

// Round 2
// 504.510 us; speedup vs baseline: 1.2781x; 1.2781x over previous
//
#include <hip/hip_runtime.h>
#include <hip/hip_bf16.h>
#include <stddef.h>

typedef __attribute__((ext_vector_type(8))) short short8;
typedef __attribute__((ext_vector_type(4))) short short4v;
typedef __attribute__((ext_vector_type(4))) float floatx4;

#define N_ 4
#define C_ 256
#define H_ 128
#define W_ 128
#define HW_ (H_*W_)
#define CD_ 64     // C/4
#define E_ 36      // k2*up2
#define OC_ 256

// round-to-nearest-even f32 -> bf16 bits
static __device__ __forceinline__ unsigned short f2bf(float f) {
    union { float f; unsigned u; } v; v.f = f;
    unsigned r = v.u + 0x7fff + ((v.u >> 16) & 1);
    return (unsigned short)(r >> 16);
}

// ---------------- Kernel 0: w_out -> bf16 ----------------
__global__ __launch_bounds__(256) void k_prep(const float* __restrict__ wo,
                                              short* __restrict__ wob) {
    int i = (blockIdx.x * 256 + threadIdx.x) * 4;
    float4 v = *(const float4*)&wo[i];
    short4v s;
    s.x = (short)f2bf(v.x); s.y = (short)f2bf(v.y);
    s.z = (short)f2bf(v.z); s.w = (short)f2bf(v.w);
    *(short4v*)&wob[i] = s;
}

// ---------------- Kernel 1: 1x1 down conv as f32 GEMM ----------------
// grid 256 = n(4) * pxchunk(64 of 256px); 512 thr; tile M=64 x N=256, K=256/32
#define WST 68
#define XST 260
__global__ __launch_bounds__(512) void k_down(
    const float* __restrict__ x, const float* __restrict__ wd,
    const float* __restrict__ bd, float* __restrict__ t)
{
    __shared__ float Wsm[32 * WST];   // [k][o]
    __shared__ float Xs[32 * XST];    // [k][px]
    int tid = threadIdx.x;
    int bx = blockIdx.x;
    int n = bx >> 6;
    int px0 = (bx & 63) * 256;
    int mg = tid >> 5;               // 0..15 -> o = mg*4
    int ng = tid & 31;               // px group of 8
    float acc[4][8];
    #pragma unroll
    for (int i = 0; i < 4; i++)
        #pragma unroll
        for (int j = 0; j < 8; j++) acc[i][j] = 0.f;

    for (int c0 = 0; c0 < C_; c0 += 32) {
        // stage W chunk (transpose): 64o x 32k
        {
            int o = tid >> 3, kb = tid & 7;
            float4 wv = *(const float4*)&wd[o * C_ + c0 + kb * 4];
            Wsm[(kb * 4 + 0) * WST + o] = wv.x;
            Wsm[(kb * 4 + 1) * WST + o] = wv.y;
            Wsm[(kb * 4 + 2) * WST + o] = wv.z;
            Wsm[(kb * 4 + 3) * WST + o] = wv.w;
        }
        // stage X chunk: 32c x 256px
        {
            int c = tid >> 4, pg = tid & 15;
            const float* xp = &x[((size_t)n * C_ + c0 + c) * HW_ + px0 + pg * 16];
            #pragma unroll
            for (int i = 0; i < 4; i++) {
                float4 v = *(const float4*)(xp + i * 4);
                *(float4*)&Xs[c * XST + pg * 16 + i * 4] = v;
            }
        }
        __syncthreads();
        #pragma unroll 4
        for (int k = 0; k < 32; k++) {
            float4 wv = *(const float4*)&Wsm[k * WST + mg * 4];
            float4 xa = *(const float4*)&Xs[k * XST + ng * 8];
            float4 xb = *(const float4*)&Xs[k * XST + ng * 8 + 4];
            float xs[8] = {xa.x, xa.y, xa.z, xa.w, xb.x, xb.y, xb.z, xb.w};
            float ws[4] = {wv.x, wv.y, wv.z, wv.w};
            #pragma unroll
            for (int i = 0; i < 4; i++)
                #pragma unroll
                for (int j = 0; j < 8; j++)
                    acc[i][j] = fmaf(ws[i], xs[j], acc[i][j]);
        }
        __syncthreads();
    }
    #pragma unroll
    for (int i = 0; i < 4; i++) {
        int o = mg * 4 + i;
        float b = bd[o];
        float* tp = &t[((size_t)n * CD_ + o) * HW_ + px0 + ng * 8];
        float4 r0, r1;
        r0.x = acc[i][0] + b; r0.y = acc[i][1] + b; r0.z = acc[i][2] + b; r0.w = acc[i][3] + b;
        r1.x = acc[i][4] + b; r1.y = acc[i][5] + b; r1.z = acc[i][6] + b; r1.w = acc[i][7] + b;
        *(float4*)tp = r0;
        *(float4*)(tp + 4) = r1;
    }
}

// ---------------- Kernel 2: 3x3 enc conv + softmax, split by q ----------------
// grid 1024 = q(4) * pxblk(256); 256 thr, 1 px/thread, 9 e's per thread
__global__ __launch_bounds__(256) void k_enc(
    const float* __restrict__ t, const float* __restrict__ we,
    const float* __restrict__ be, float* __restrict__ kern)
{
    int q = blockIdx.x >> 8;
    int px = (blockIdx.x & 255) * 256 + threadIdx.x;   // 0..65535
    int n = px >> 14;
    int hw = px & (HW_ - 1);
    int h = hw >> 7, w = hw & (W_ - 1);
    float acc[9];
    #pragma unroll
    for (int k = 0; k < 9; k++) acc[k] = be[k * 4 + q];
    const float* tb = t + (size_t)n * CD_ * HW_;
    bool hv[3], wv[3];
    int ho[3], wo_[3];
    #pragma unroll
    for (int d = 0; d < 3; d++) {
        int hh = h + d - 1; hv[d] = (hh >= 0 && hh < H_); ho[d] = hh * W_;
        int ww = w + d - 1; wv[d] = (ww >= 0 && ww < W_); wo_[d] = ww;
    }
    for (int c = 0; c < CD_; c++) {
        float tv[9];
        #pragma unroll
        for (int di = 0; di < 3; di++)
            #pragma unroll
            for (int dj = 0; dj < 3; dj++)
                tv[di * 3 + dj] = (hv[di] && wv[dj]) ? tb[c * HW_ + ho[di] + wo_[dj]] : 0.f;
        #pragma unroll
        for (int k = 0; k < 9; k++) {
            const float* wp = we + ((size_t)(k * 4 + q) * CD_ + c) * 9;  // uniform -> s_load
            float a = acc[k];
            #pragma unroll
            for (int ij = 0; ij < 9; ij++) a = fmaf(tv[ij], wp[ij], a);
            acc[k] = a;
        }
    }
    float m = acc[0];
    #pragma unroll
    for (int k = 1; k < 9; k++) m = fmaxf(m, acc[k]);
    float ex[9], s = 0.f;
    #pragma unroll
    for (int k = 0; k < 9; k++) { ex[k] = __expf(acc[k] - m); s += ex[k]; }
    float inv = 1.f / s;
    float* kp = kern + (size_t)px * E_ + q;
    #pragma unroll
    for (int k = 0; k < 9; k++) kp[k * 4] = ex[k] * inv;
}

// ---------------- Kernel 3: fused reassembly + pixel shuffle + 1x1 conv (MFMA) ----------------
// grid 2048 = n(4) * ty(32) * tx(16); 512 thr = 8 waves (2M x 4N)
// block tile: 256 out-ch x 128 cols (32 px * 4 q); K=256 in chunks of 32
#define XS 36   // Xsm row stride (words), 144 B = 16B-aligned
__global__ __launch_bounds__(512, 4) void k_main(
    const float* __restrict__ x, const float* __restrict__ kern,
    const short* __restrict__ wob, const float* __restrict__ bo,
    float* __restrict__ y)
{
    __shared__ short Bsm[2][128 * 40];   // 2 x 10 KB
    __shared__ float Xsm[2][60 * XS];    // 2 x 8.6 KB, [spatial][ch]
    __shared__ float Ksm[32 * 36];       // [p][e]
    __shared__ float bsm[256];

    int tid = threadIdx.x;
    int bx = blockIdx.x;
    int n = bx >> 9;
    int rem = bx & 511;
    int ty = rem >> 4, tx = rem & 15;
    int h0 = ty * 4, w0 = tx * 8;

    int lane = tid & 63;
    int wave = tid >> 6;
    int wm = wave >> 2, wn = wave & 3;

    // B-build role: p-pixel, 4-channel group, q-half
    int p = tid >> 4;          // 0..31
    int cg = (tid >> 1) & 7;   // 0..7 (4 channels each)
    int qh = tid & 1;          // q = 2*qh + qi
    int py = p >> 3, pxl = p & 7;

    if (tid < 256) bsm[tid] = bo[tid];
    for (int idx = tid; idx < 32 * 36; idx += 512) {
        int pp = idx / 36, e = idx - pp * 36;
        int gh = h0 + (pp >> 3), gw = w0 + (pp & 7);
        Ksm[idx] = kern[((size_t)((n * H_ + gh) * W_) + gw) * E_ + e];
    }

    auto stage_x = [&](int c0, int buf) {
        for (int idx = tid; idx < 1920; idx += 512) {
            int c = idx / 60, s = idx - c * 60;
            int hh = s / 10, ww = s - hh * 10;
            int gh = h0 + hh - 1, gw = w0 + ww - 1;
            float v = 0.f;
            if (gh >= 0 && gh < H_ && gw >= 0 && gw < W_)
                v = x[((size_t)n * C_ + c0 + c) * HW_ + gh * W_ + gw];
            Xsm[buf][s * XS + c] = v;
        }
    };

    stage_x(0, 0);
    __syncthreads();

    // hoist per-thread kernel weights: kv[qi][tap]
    float kv[2][9];
    #pragma unroll
    for (int qi = 0; qi < 2; qi++)
        #pragma unroll
        for (int k = 0; k < 9; k++)
            kv[qi][k] = Ksm[p * 36 + k * 4 + 2 * qh + qi];

    floatx4 acc[8][2];
    #pragma unroll
    for (int fm = 0; fm < 8; fm++) {
        acc[fm][0] = (floatx4)0.f;
        acc[fm][1] = (floatx4)0.f;
    }

    for (int kc = 0; kc < 8; kc++) {
        int buf = kc & 1;
        int c0 = kc * 32;
        // ---- build B(kc): 4 ch x 2 q per thread, 9 x ds_read_b128 ----
        float vals[2][4];
        #pragma unroll
        for (int qi = 0; qi < 2; qi++)
            #pragma unroll
            for (int ci = 0; ci < 4; ci++) vals[qi][ci] = 0.f;
        #pragma unroll
        for (int di = 0; di < 3; di++)
            #pragma unroll
            for (int dj = 0; dj < 3; dj++) {
                float4 xv = *(const float4*)&Xsm[buf][((py + di) * 10 + pxl + dj) * XS + cg * 4];
                float k0 = kv[0][di * 3 + dj], k1 = kv[1][di * 3 + dj];
                vals[0][0] = fmaf(xv.x, k0, vals[0][0]);
                vals[0][1] = fmaf(xv.y, k0, vals[0][1]);
                vals[0][2] = fmaf(xv.z, k0, vals[0][2]);
                vals[0][3] = fmaf(xv.w, k0, vals[0][3]);
                vals[1][0] = fmaf(xv.x, k1, vals[1][0]);
                vals[1][1] = fmaf(xv.y, k1, vals[1][1]);
                vals[1][2] = fmaf(xv.z, k1, vals[1][2]);
                vals[1][3] = fmaf(xv.w, k1, vals[1][3]);
            }
        #pragma unroll
        for (int qi = 0; qi < 2; qi++) {
            short4v sv;
            sv.x = (short)f2bf(vals[qi][0]);
            sv.y = (short)f2bf(vals[qi][1]);
            sv.z = (short)f2bf(vals[qi][2]);
            sv.w = (short)f2bf(vals[qi][3]);
            int col = p * 4 + 2 * qh + qi;
            *(short4v*)&Bsm[buf][col * 40 + cg * 4] = sv;
        }
        // ---- stage X(kc+1) into other buffer (overlaps) ----
        if (kc < 7) stage_x(c0 + 32, buf ^ 1);
        __syncthreads();
        // ---- MFMA: A from global (L1/L2-hot bf16 w_out), B from LDS ----
        short8 bfrag[2];
        #pragma unroll
        for (int fn = 0; fn < 2; fn++) {
            int col = wn * 32 + fn * 16 + (lane & 15);
            bfrag[fn] = *(const short8*)&Bsm[buf][col * 40 + (lane >> 4) * 8];
        }
        #pragma unroll
        for (int fm = 0; fm < 8; fm++) {
            int row = wm * 128 + fm * 16 + (lane & 15);
            short8 af = *(const short8*)&wob[(size_t)row * C_ + c0 + (lane >> 4) * 8];
            acc[fm][0] = __builtin_amdgcn_mfma_f32_16x16x32_bf16(af, bfrag[0], acc[fm][0], 0, 0, 0);
            acc[fm][1] = __builtin_amdgcn_mfma_f32_16x16x32_bf16(af, bfrag[1], acc[fm][1], 0, 0, 0);
        }
    }
    // epilogue: D row=(lane>>4)*4+i, col=lane&15; pixel shuffle + bias
    #pragma unroll
    for (int fm = 0; fm < 8; fm++) {
        int o0 = wm * 128 + fm * 16 + ((lane >> 4) << 2);
        #pragma unroll
        for (int fn = 0; fn < 2; fn++) {
            int col = wn * 32 + fn * 16 + (lane & 15);
            int pp = col >> 2, q = col & 3;
            int ppy = pp >> 3, ppx = pp & 7;
            int h2 = ((h0 + ppy) << 1) + (q >> 1);
            int w2 = ((w0 + ppx) << 1) + (q & 1);
            float* yp = y + (size_t)n * OC_ * 65536 + (size_t)h2 * 256 + w2;
            #pragma unroll
            for (int i = 0; i < 4; i++) {
                int oo = o0 + i;
                yp[(size_t)oo * 65536] = acc[fm][fn][i] + bsm[oo];
            }
        }
    }
}

extern "C" void kernel_launch(void* const* d_in, const int* in_sizes, int n_in,
                              void* d_out, int out_size, void* d_ws, size_t ws_size,
                              hipStream_t stream) {
    const float* x  = (const float*)d_in[0];
    const float* wd = (const float*)d_in[1];
    const float* bd = (const float*)d_in[2];
    const float* we = (const float*)d_in[3];
    const float* be = (const float*)d_in[4];
    const float* wo = (const float*)d_in[5];
    const float* bo = (const float*)d_in[6];
    float* y = (float*)d_out;

    float* t    = (float*)d_ws;                       // [4][64][16384] = 16.8 MB
    float* kern = t + (size_t)N_ * CD_ * HW_;         // [65536][36]    =  9.4 MB
    short* wob  = (short*)(kern + (size_t)N_ * HW_ * E_);  // [256][256] bf16

    k_prep<<<64,   256, 0, stream>>>(wo, wob);
    k_down<<<256,  512, 0, stream>>>(x, wd, bd, t);
    k_enc <<<1024, 256, 0, stream>>>(t, we, be, kern);
    k_main<<<2048, 512, 0, stream>>>(x, kern, wob, bo, y);
}

// Round 3
// 272.997 us; speedup vs baseline: 2.3621x; 1.8480x over previous
//
#include <hip/hip_runtime.h>
#include <hip/hip_bf16.h>
#include <stddef.h>

typedef __attribute__((ext_vector_type(8))) short short8;
typedef __attribute__((ext_vector_type(4))) short short4v;
typedef __attribute__((ext_vector_type(4))) float floatx4;

#define N_ 4
#define C_ 256
#define H_ 128
#define W_ 128
#define HW_ (H_*W_)
#define CD_ 64     // C/4
#define E_ 36      // k2*up2
#define OC_ 256

// round-to-nearest-even f32 -> bf16 bits
static __device__ __forceinline__ unsigned short f2bf(float f) {
    union { float f; unsigned u; } v; v.f = f;
    unsigned r = v.u + 0x7fff + ((v.u >> 16) & 1);
    return (unsigned short)(r >> 16);
}

// ---------------- Kernel 0: w_out -> bf16 ----------------
__global__ __launch_bounds__(256) void k_prep(const float* __restrict__ wo,
                                              short* __restrict__ wob) {
    int i = (blockIdx.x * 256 + threadIdx.x) * 4;
    float4 v = *(const float4*)&wo[i];
    short4v s;
    s.x = (short)f2bf(v.x); s.y = (short)f2bf(v.y);
    s.z = (short)f2bf(v.z); s.w = (short)f2bf(v.w);
    *(short4v*)&wob[i] = s;
}

// ---------------- Kernel 1: 1x1 down conv as f32 GEMM ----------------
// grid 256 = n(4) * pxchunk(64 of 256px); 512 thr; tile M=64 x N=256, K=256/32
#define WST 68
#define XST 260
__global__ __launch_bounds__(512) void k_down(
    const float* __restrict__ x, const float* __restrict__ wd,
    const float* __restrict__ bd, float* __restrict__ t)
{
    __shared__ float Wsm[32 * WST];   // [k][o]
    __shared__ float Xs[32 * XST];    // [k][px]
    int tid = threadIdx.x;
    int bx = blockIdx.x;
    int n = bx >> 6;
    int px0 = (bx & 63) * 256;
    int mg = tid >> 5;               // 0..15 -> o = mg*4
    int ng = tid & 31;               // px group of 8
    float acc[4][8];
    #pragma unroll
    for (int i = 0; i < 4; i++)
        #pragma unroll
        for (int j = 0; j < 8; j++) acc[i][j] = 0.f;

    for (int c0 = 0; c0 < C_; c0 += 32) {
        // stage W chunk (transpose): 64o x 32k
        {
            int o = tid >> 3, kb = tid & 7;
            float4 wv = *(const float4*)&wd[o * C_ + c0 + kb * 4];
            Wsm[(kb * 4 + 0) * WST + o] = wv.x;
            Wsm[(kb * 4 + 1) * WST + o] = wv.y;
            Wsm[(kb * 4 + 2) * WST + o] = wv.z;
            Wsm[(kb * 4 + 3) * WST + o] = wv.w;
        }
        // stage X chunk: 32c x 256px
        {
            int c = tid >> 4, pg = tid & 15;
            const float* xp = &x[((size_t)n * C_ + c0 + c) * HW_ + px0 + pg * 16];
            #pragma unroll
            for (int i = 0; i < 4; i++) {
                float4 v = *(const float4*)(xp + i * 4);
                *(float4*)&Xs[c * XST + pg * 16 + i * 4] = v;
            }
        }
        __syncthreads();
        #pragma unroll 4
        for (int k = 0; k < 32; k++) {
            float4 wv = *(const float4*)&Wsm[k * WST + mg * 4];
            float4 xa = *(const float4*)&Xs[k * XST + ng * 8];
            float4 xb = *(const float4*)&Xs[k * XST + ng * 8 + 4];
            float xs[8] = {xa.x, xa.y, xa.z, xa.w, xb.x, xb.y, xb.z, xb.w};
            float ws[4] = {wv.x, wv.y, wv.z, wv.w};
            #pragma unroll
            for (int i = 0; i < 4; i++)
                #pragma unroll
                for (int j = 0; j < 8; j++)
                    acc[i][j] = fmaf(ws[i], xs[j], acc[i][j]);
        }
        __syncthreads();
    }
    #pragma unroll
    for (int i = 0; i < 4; i++) {
        int o = mg * 4 + i;
        float b = bd[o];
        float* tp = &t[((size_t)n * CD_ + o) * HW_ + px0 + ng * 8];
        float4 r0, r1;
        r0.x = acc[i][0] + b; r0.y = acc[i][1] + b; r0.z = acc[i][2] + b; r0.w = acc[i][3] + b;
        r1.x = acc[i][4] + b; r1.y = acc[i][5] + b; r1.z = acc[i][6] + b; r1.w = acc[i][7] + b;
        *(float4*)tp = r0;
        *(float4*)(tp + 4) = r1;
    }
}

// ---------------- Kernel 2: 3x3 enc conv + softmax, split by q ----------------
// grid 1024 = q(4) * pxblk(256); 256 thr, 1 px/thread, 9 e's per thread
__global__ __launch_bounds__(256) void k_enc(
    const float* __restrict__ t, const float* __restrict__ we,
    const float* __restrict__ be, float* __restrict__ kern)
{
    int q = blockIdx.x >> 8;
    int px = (blockIdx.x & 255) * 256 + threadIdx.x;   // 0..65535
    int n = px >> 14;
    int hw = px & (HW_ - 1);
    int h = hw >> 7, w = hw & (W_ - 1);
    float acc[9];
    #pragma unroll
    for (int k = 0; k < 9; k++) acc[k] = be[k * 4 + q];
    const float* tb = t + (size_t)n * CD_ * HW_;
    bool hv[3], wv[3];
    int ho[3], wo_[3];
    #pragma unroll
    for (int d = 0; d < 3; d++) {
        int hh = h + d - 1; hv[d] = (hh >= 0 && hh < H_); ho[d] = hh * W_;
        int ww = w + d - 1; wv[d] = (ww >= 0 && ww < W_); wo_[d] = ww;
    }
    for (int c = 0; c < CD_; c++) {
        float tv[9];
        #pragma unroll
        for (int di = 0; di < 3; di++)
            #pragma unroll
            for (int dj = 0; dj < 3; dj++)
                tv[di * 3 + dj] = (hv[di] && wv[dj]) ? tb[c * HW_ + ho[di] + wo_[dj]] : 0.f;
        #pragma unroll
        for (int k = 0; k < 9; k++) {
            const float* wp = we + ((size_t)(k * 4 + q) * CD_ + c) * 9;  // uniform -> s_load
            float a = acc[k];
            #pragma unroll
            for (int ij = 0; ij < 9; ij++) a = fmaf(tv[ij], wp[ij], a);
            acc[k] = a;
        }
    }
    float m = acc[0];
    #pragma unroll
    for (int k = 1; k < 9; k++) m = fmaxf(m, acc[k]);
    float ex[9], s = 0.f;
    #pragma unroll
    for (int k = 0; k < 9; k++) { ex[k] = __expf(acc[k] - m); s += ex[k]; }
    float inv = 1.f / s;
    float* kp = kern + (size_t)px * E_ + q;
    #pragma unroll
    for (int k = 0; k < 9; k++) kp[k * 4] = ex[k] * inv;
}

// ---------------- Kernel 3: fused reassembly + pixel shuffle + 1x1 conv (MFMA) ----------------
// grid 2048 = n(4) * ty(32) * tx(16); 512 thr = 8 waves (2M x 4N)
// block tile: 256 out-ch (M) x 128 cols (N); col = h2l*16 + w2l over the
// 4x8-pixel x 2x2-subpixel output tile -> 64-B coalesced y stores.
// K=256 in 8 chunks of 32. A dbuf in LDS; B, X single-buffered; 2 barriers/chunk.
#define XS 36   // Xsm row stride (words), 144 B
__global__ __launch_bounds__(512, 4) void k_main(
    const float* __restrict__ x, const float* __restrict__ kern,
    const short* __restrict__ wob, const float* __restrict__ bo,
    float* __restrict__ y)
{
    __shared__ short Asm[2][256 * 40];   // 2 x 20 KB  (w_out chunk, bf16)
    __shared__ short Bsm[128 * 40];      // 10 KB      (reassembled cols, bf16)
    __shared__ float Xsm[60 * XS];       // 8.6 KB     [spatial][ch]
    __shared__ float Ksm[32 * 36];       // 4.6 KB     [p][e]
    __shared__ float bsm[256];

    int tid = threadIdx.x;
    int bx = blockIdx.x;
    int n = bx >> 9;
    int rem = bx & 511;
    int ty = rem >> 4, tx = rem & 15;
    int h0 = ty * 4, w0 = tx * 8;

    int lane = tid & 63;
    int wave = tid >> 6;
    int wm = wave >> 2, wn = wave & 3;

    // B-build role: p-pixel, 4-channel group, q row-half
    int p = tid >> 4;          // 0..31
    int cg = (tid >> 1) & 7;   // 0..7 (4 channels each)
    int qh = tid & 1;          // q = 2*qh + qj
    int py = p >> 3, pxl = p & 7;

    if (tid < 256) bsm[tid] = bo[tid];
    for (int idx = tid; idx < 32 * 36; idx += 512) {
        int pp = idx / 36, e = idx - pp * 36;
        int gh = h0 + (pp >> 3), gw = w0 + (pp & 7);
        Ksm[idx] = kern[((size_t)((n * H_ + gh) * W_) + gw) * E_ + e];
    }
    __syncthreads();

    // hoist per-thread kernel weights: kv[qj][tap]
    float kv[2][9];
    #pragma unroll
    for (int qj = 0; qj < 2; qj++)
        #pragma unroll
        for (int k = 0; k < 9; k++)
            kv[qj][k] = Ksm[p * 36 + k * 4 + 2 * qh + qj];

    floatx4 acc[8][2];
    #pragma unroll
    for (int fm = 0; fm < 8; fm++) {
        acc[fm][0] = (floatx4)0.f;
        acc[fm][1] = (floatx4)0.f;
    }

    for (int kc = 0; kc < 8; kc++) {
        int ab = kc & 1;
        int c0 = kc * 32;
        // ---- stage A(kc): w_out rows, 32 ch chunk -> bf16 LDS (dbuf) ----
        {
            int o = tid >> 1, half = tid & 1;
            const short* src = &wob[(size_t)o * C_ + c0 + half * 16];
            short8 a0 = *(const short8*)src;
            short8 a1 = *(const short8*)(src + 8);
            short* dst = &Asm[ab][o * 40 + half * 16];
            *(short8*)dst = a0;
            *(short8*)(dst + 8) = a1;
        }
        // ---- stage X(kc): halo tile [spatial][ch] ----
        for (int idx = tid; idx < 1920; idx += 512) {
            int c = idx / 60, s = idx - c * 60;
            int hh = s / 10, ww = s - hh * 10;
            int gh = h0 + hh - 1, gw = w0 + ww - 1;
            float v = 0.f;
            if (gh >= 0 && gh < H_ && gw >= 0 && gw < W_)
                v = x[((size_t)n * C_ + c0 + c) * HW_ + gh * W_ + gw];
            Xsm[s * XS + c] = v;
        }
        __syncthreads();
        // ---- build B(kc): 4 ch x 2 cols per thread, 9 x ds_read_b128 ----
        {
            float vals[2][4];
            #pragma unroll
            for (int qj = 0; qj < 2; qj++)
                #pragma unroll
                for (int ci = 0; ci < 4; ci++) vals[qj][ci] = 0.f;
            #pragma unroll
            for (int di = 0; di < 3; di++)
                #pragma unroll
                for (int dj = 0; dj < 3; dj++) {
                    float4 xv = *(const float4*)&Xsm[((py + di) * 10 + pxl + dj) * XS + cg * 4];
                    float k0 = kv[0][di * 3 + dj], k1 = kv[1][di * 3 + dj];
                    vals[0][0] = fmaf(xv.x, k0, vals[0][0]);
                    vals[0][1] = fmaf(xv.y, k0, vals[0][1]);
                    vals[0][2] = fmaf(xv.z, k0, vals[0][2]);
                    vals[0][3] = fmaf(xv.w, k0, vals[0][3]);
                    vals[1][0] = fmaf(xv.x, k1, vals[1][0]);
                    vals[1][1] = fmaf(xv.y, k1, vals[1][1]);
                    vals[1][2] = fmaf(xv.z, k1, vals[1][2]);
                    vals[1][3] = fmaf(xv.w, k1, vals[1][3]);
                }
            #pragma unroll
            for (int qj = 0; qj < 2; qj++) {
                short4v sv;
                sv.x = (short)f2bf(vals[qj][0]);
                sv.y = (short)f2bf(vals[qj][1]);
                sv.z = (short)f2bf(vals[qj][2]);
                sv.w = (short)f2bf(vals[qj][3]);
                // col = h2l*16 + w2l ; h2l = py*2+qh, w2l = pxl*2+qj
                int col = (py * 2 + qh) * 16 + pxl * 2 + qj;
                *(short4v*)&Bsm[col * 40 + cg * 4] = sv;
            }
        }
        __syncthreads();
        // ---- MFMA: A from LDS dbuf, B from LDS ----
        {
            short8 bfrag[2];
            #pragma unroll
            for (int fn = 0; fn < 2; fn++) {
                int col = wn * 32 + fn * 16 + (lane & 15);
                bfrag[fn] = *(const short8*)&Bsm[col * 40 + (lane >> 4) * 8];
            }
            #pragma unroll
            for (int fm = 0; fm < 8; fm++) {
                int row = wm * 128 + fm * 16 + (lane & 15);
                short8 af = *(const short8*)&Asm[ab][row * 40 + (lane >> 4) * 8];
                acc[fm][0] = __builtin_amdgcn_mfma_f32_16x16x32_bf16(af, bfrag[0], acc[fm][0], 0, 0, 0);
                acc[fm][1] = __builtin_amdgcn_mfma_f32_16x16x32_bf16(af, bfrag[1], acc[fm][1], 0, 0, 0);
            }
        }
    }
    // epilogue: D row=(lane>>4)*4+i, col=lane&15; col -> (h2l, w2l) contiguous
    #pragma unroll
    for (int fm = 0; fm < 8; fm++) {
        int o0 = wm * 128 + fm * 16 + ((lane >> 4) << 2);
        #pragma unroll
        for (int fn = 0; fn < 2; fn++) {
            int col = wn * 32 + fn * 16 + (lane & 15);
            int h2 = h0 * 2 + (col >> 4);
            int w2 = w0 * 2 + (col & 15);
            float* yp = y + (size_t)n * OC_ * 65536 + (size_t)h2 * 256 + w2;
            #pragma unroll
            for (int i = 0; i < 4; i++) {
                int oo = o0 + i;
                yp[(size_t)oo * 65536] = acc[fm][fn][i] + bsm[oo];
            }
        }
    }
}

extern "C" void kernel_launch(void* const* d_in, const int* in_sizes, int n_in,
                              void* d_out, int out_size, void* d_ws, size_t ws_size,
                              hipStream_t stream) {
    const float* x  = (const float*)d_in[0];
    const float* wd = (const float*)d_in[1];
    const float* bd = (const float*)d_in[2];
    const float* we = (const float*)d_in[3];
    const float* be = (const float*)d_in[4];
    const float* wo = (const float*)d_in[5];
    const float* bo = (const float*)d_in[6];
    float* y = (float*)d_out;

    float* t    = (float*)d_ws;                       // [4][64][16384] = 16.8 MB
    float* kern = t + (size_t)N_ * CD_ * HW_;         // [65536][36]    =  9.4 MB
    short* wob  = (short*)(kern + (size_t)N_ * HW_ * E_);  // [256][256] bf16

    k_prep<<<64,   256, 0, stream>>>(wo, wob);
    k_down<<<256,  512, 0, stream>>>(x, wd, bd, t);
    k_enc <<<1024, 256, 0, stream>>>(t, we, be, kern);
    k_main<<<2048, 512, 0, stream>>>(x, kern, wob, bo, y);
}

// Round 4
// 225.051 us; speedup vs baseline: 2.8653x; 1.2130x over previous
//
#include <hip/hip_runtime.h>
#include <hip/hip_bf16.h>
#include <stddef.h>

typedef __attribute__((ext_vector_type(8))) short short8;
typedef __attribute__((ext_vector_type(4))) short short4v;
typedef __attribute__((ext_vector_type(4))) float floatx4;

#define N_ 4
#define C_ 256
#define H_ 128
#define W_ 128
#define HW_ (H_*W_)
#define CD_ 64     // C/4
#define E_ 36      // k2*up2
#define OC_ 256

// round-to-nearest-even f32 -> bf16 bits
static __device__ __forceinline__ unsigned short f2bf(float f) {
    union { float f; unsigned u; } v; v.f = f;
    unsigned r = v.u + 0x7fff + ((v.u >> 16) & 1);
    return (unsigned short)(r >> 16);
}
static __device__ __forceinline__ float bf2f(unsigned short s) {
    union { unsigned u; float f; } v; v.u = ((unsigned)s) << 16;
    return v.f;
}

// ---------------- Kernel 0: w_out -> bf16 ----------------
__global__ __launch_bounds__(256) void k_prep(const float* __restrict__ wo,
                                              short* __restrict__ wob) {
    int i = (blockIdx.x * 256 + threadIdx.x) * 4;
    float4 v = *(const float4*)&wo[i];
    short4v s;
    s.x = (short)f2bf(v.x); s.y = (short)f2bf(v.y);
    s.z = (short)f2bf(v.z); s.w = (short)f2bf(v.w);
    *(short4v*)&wob[i] = s;
}

// ---------------- Kernel 1: 1x1 down conv as f32 GEMM ----------------
// grid 256 = n(4) * pxchunk(64 of 256px); 512 thr; tile M=64 x N=256, K=256/32
#define WST 68
#define XST 260
__global__ __launch_bounds__(512) void k_down(
    const float* __restrict__ x, const float* __restrict__ wd,
    const float* __restrict__ bd, float* __restrict__ t)
{
    __shared__ float Wsm[32 * WST];   // [k][o]
    __shared__ float Xs[32 * XST];    // [k][px]
    int tid = threadIdx.x;
    int bx = blockIdx.x;
    int n = bx >> 6;
    int px0 = (bx & 63) * 256;
    int mg = tid >> 5;               // 0..15 -> o = mg*4
    int ng = tid & 31;               // px group of 8
    float acc[4][8];
    #pragma unroll
    for (int i = 0; i < 4; i++)
        #pragma unroll
        for (int j = 0; j < 8; j++) acc[i][j] = 0.f;

    for (int c0 = 0; c0 < C_; c0 += 32) {
        {
            int o = tid >> 3, kb = tid & 7;
            float4 wv = *(const float4*)&wd[o * C_ + c0 + kb * 4];
            Wsm[(kb * 4 + 0) * WST + o] = wv.x;
            Wsm[(kb * 4 + 1) * WST + o] = wv.y;
            Wsm[(kb * 4 + 2) * WST + o] = wv.z;
            Wsm[(kb * 4 + 3) * WST + o] = wv.w;
        }
        {
            int c = tid >> 4, pg = tid & 15;
            const float* xp = &x[((size_t)n * C_ + c0 + c) * HW_ + px0 + pg * 16];
            #pragma unroll
            for (int i = 0; i < 4; i++) {
                float4 v = *(const float4*)(xp + i * 4);
                *(float4*)&Xs[c * XST + pg * 16 + i * 4] = v;
            }
        }
        __syncthreads();
        #pragma unroll 4
        for (int k = 0; k < 32; k++) {
            float4 wv = *(const float4*)&Wsm[k * WST + mg * 4];
            float4 xa = *(const float4*)&Xs[k * XST + ng * 8];
            float4 xb = *(const float4*)&Xs[k * XST + ng * 8 + 4];
            float xs[8] = {xa.x, xa.y, xa.z, xa.w, xb.x, xb.y, xb.z, xb.w};
            float ws[4] = {wv.x, wv.y, wv.z, wv.w};
            #pragma unroll
            for (int i = 0; i < 4; i++)
                #pragma unroll
                for (int j = 0; j < 8; j++)
                    acc[i][j] = fmaf(ws[i], xs[j], acc[i][j]);
        }
        __syncthreads();
    }
    #pragma unroll
    for (int i = 0; i < 4; i++) {
        int o = mg * 4 + i;
        float b = bd[o];
        float* tp = &t[((size_t)n * CD_ + o) * HW_ + px0 + ng * 8];
        float4 r0, r1;
        r0.x = acc[i][0] + b; r0.y = acc[i][1] + b; r0.z = acc[i][2] + b; r0.w = acc[i][3] + b;
        r1.x = acc[i][4] + b; r1.y = acc[i][5] + b; r1.z = acc[i][6] + b; r1.w = acc[i][7] + b;
        *(float4*)tp = r0;
        *(float4*)(tp + 4) = r1;
    }
}

// ---------------- Kernel 2: 3x3 enc conv + softmax, split by q ----------------
__global__ __launch_bounds__(256) void k_enc(
    const float* __restrict__ t, const float* __restrict__ we,
    const float* __restrict__ be, float* __restrict__ kern)
{
    int q = blockIdx.x >> 8;
    int px = (blockIdx.x & 255) * 256 + threadIdx.x;   // 0..65535
    int n = px >> 14;
    int hw = px & (HW_ - 1);
    int h = hw >> 7, w = hw & (W_ - 1);
    float acc[9];
    #pragma unroll
    for (int k = 0; k < 9; k++) acc[k] = be[k * 4 + q];
    const float* tb = t + (size_t)n * CD_ * HW_;
    bool hv[3], wv[3];
    int ho[3], wo_[3];
    #pragma unroll
    for (int d = 0; d < 3; d++) {
        int hh = h + d - 1; hv[d] = (hh >= 0 && hh < H_); ho[d] = hh * W_;
        int ww = w + d - 1; wv[d] = (ww >= 0 && ww < W_); wo_[d] = ww;
    }
    for (int c = 0; c < CD_; c++) {
        float tv[9];
        #pragma unroll
        for (int di = 0; di < 3; di++)
            #pragma unroll
            for (int dj = 0; dj < 3; dj++)
                tv[di * 3 + dj] = (hv[di] && wv[dj]) ? tb[c * HW_ + ho[di] + wo_[dj]] : 0.f;
        #pragma unroll
        for (int k = 0; k < 9; k++) {
            const float* wp = we + ((size_t)(k * 4 + q) * CD_ + c) * 9;  // uniform -> s_load
            float a = acc[k];
            #pragma unroll
            for (int ij = 0; ij < 9; ij++) a = fmaf(tv[ij], wp[ij], a);
            acc[k] = a;
        }
    }
    float m = acc[0];
    #pragma unroll
    for (int k = 1; k < 9; k++) m = fmaxf(m, acc[k]);
    float ex[9], s = 0.f;
    #pragma unroll
    for (int k = 0; k < 9; k++) { ex[k] = __expf(acc[k] - m); s += ex[k]; }
    float inv = 1.f / s;
    float* kp = kern + (size_t)px * E_ + q;
    #pragma unroll
    for (int k = 0; k < 9; k++) kp[k * 4] = ex[k] * inv;
}

// ---------------- Kernel 3: G = w_out @ x (bf16 MFMA, low-res) ----------------
// grid 512 = n(4) * pxblk(128 of 128 px); 512 thr = 8 waves (2M x 4N)
// tile M=256(o) x N=128(px), K=256 in 8 chunks of 32. A,B dbuf; 1 barrier/chunk.
__global__ __launch_bounds__(512, 4) void k_gemm(
    const float* __restrict__ x, const short* __restrict__ wob,
    short* __restrict__ G)
{
    __shared__ short Asm[2][256 * 40];   // 2 x 20 KB
    __shared__ short Bsm[2][128 * 40];   // 2 x 10 KB

    int tid = threadIdx.x;
    int bx = blockIdx.x;
    int n = bx >> 7;
    int px0 = (bx & 127) * 128;

    int lane = tid & 63;
    int wave = tid >> 6;
    int wm = wave >> 2, wn = wave & 3;

    int ao = tid >> 1, ah = tid & 1;     // A stage role
    int bpx = tid & 127, bcq = tid >> 7; // B stage role (px, 8-ch quarter)

    const float* xb = x + (size_t)n * C_ * HW_ + px0 + bpx;
    const short* wr = wob + ao * C_ + ah * 16;

    short8 a0, a1;
    float xg[8];

    auto issue = [&](int c0) {
        a0 = *(const short8*)(wr + c0);
        a1 = *(const short8*)(wr + c0 + 8);
        #pragma unroll
        for (int j = 0; j < 8; j++)
            xg[j] = xb[(size_t)(c0 + bcq * 8 + j) * HW_];
    };
    auto commit = [&](int buf) {
        short* ad = &Asm[buf][ao * 40 + ah * 16];
        *(short8*)ad = a0;
        *(short8*)(ad + 8) = a1;
        short8 bv;
        #pragma unroll
        for (int j = 0; j < 8; j++) bv[j] = (short)f2bf(xg[j]);
        *(short8*)&Bsm[buf][bpx * 40 + bcq * 8] = bv;
    };

    floatx4 acc[8][2];
    #pragma unroll
    for (int fm = 0; fm < 8; fm++) {
        acc[fm][0] = (floatx4)0.f;
        acc[fm][1] = (floatx4)0.f;
    }

    issue(0);
    commit(0);
    __syncthreads();

    for (int kc = 0; kc < 8; kc++) {
        int cur = kc & 1;
        if (kc < 7) issue((kc + 1) * 32);
        // MFMA from buf cur
        short8 bfrag[2];
        #pragma unroll
        for (int fn = 0; fn < 2; fn++) {
            int col = wn * 32 + fn * 16 + (lane & 15);
            bfrag[fn] = *(const short8*)&Bsm[cur][col * 40 + (lane >> 4) * 8];
        }
        #pragma unroll
        for (int fm = 0; fm < 8; fm++) {
            int row = wm * 128 + fm * 16 + (lane & 15);
            short8 af = *(const short8*)&Asm[cur][row * 40 + (lane >> 4) * 8];
            acc[fm][0] = __builtin_amdgcn_mfma_f32_16x16x32_bf16(af, bfrag[0], acc[fm][0], 0, 0, 0);
            acc[fm][1] = __builtin_amdgcn_mfma_f32_16x16x32_bf16(af, bfrag[1], acc[fm][1], 0, 0, 0);
        }
        if (kc < 7) {
            commit(cur ^ 1);
            __syncthreads();
        }
    }
    // epilogue: store bf16 G; D row=(lane>>4)*4+i, col=lane&15
    #pragma unroll
    for (int fm = 0; fm < 8; fm++) {
        int o0 = wm * 128 + fm * 16 + ((lane >> 4) << 2);
        #pragma unroll
        for (int fn = 0; fn < 2; fn++) {
            int col = px0 + wn * 32 + fn * 16 + (lane & 15);
            #pragma unroll
            for (int i = 0; i < 4; i++) {
                unsigned short v = f2bf(acc[fm][fn][i]);
                ((unsigned short*)G)[((size_t)n * OC_ + o0 + i) * HW_ + col] = v;
            }
        }
    }
}

// ---------------- Kernel 4: 9-tap combine + pixel shuffle + bias ----------------
// grid 2048 = n(4) * og(8 of 32 o) * hb(64 of 2 rows); 256 thr: (h-half, w)
__global__ __launch_bounds__(256) void k_up(
    const short* __restrict__ G, const float* __restrict__ kern,
    const float* __restrict__ bo, float* __restrict__ y)
{
    int bx = blockIdx.x;
    int n = bx >> 9;
    int og = (bx >> 6) & 7;
    int hb = bx & 63;
    int tid = threadIdx.x;
    int h = hb * 2 + (tid >> 7);
    int w = tid & 127;

    // per-pixel kernel weights: 36 f32, 16B-aligned
    const float* kp = kern + ((size_t)((n * H_ + h) * W_) + w) * E_;
    float kv[36];
    #pragma unroll
    for (int i = 0; i < 9; i++) {
        float4 v = *(const float4*)(kp + i * 4);
        kv[i * 4] = v.x; kv[i * 4 + 1] = v.y; kv[i * 4 + 2] = v.z; kv[i * 4 + 3] = v.w;
    }

    // tap offsets (clamped) + validity
    int off[9]; bool val[9];
    #pragma unroll
    for (int di = 0; di < 3; di++) {
        int hh = h + di - 1;
        bool hvv = (hh >= 0 && hh < H_);
        int hc = hvv ? hh : h;
        #pragma unroll
        for (int dj = 0; dj < 3; dj++) {
            int ww = w + dj - 1;
            bool wvv = (ww >= 0 && ww < W_);
            int wc = wvv ? ww : w;
            off[di * 3 + dj] = hc * W_ + wc;
            val[di * 3 + dj] = hvv && wvv;
        }
    }

    const unsigned short* Gn = (const unsigned short*)G + ((size_t)n * OC_ + og * 32) * HW_;
    size_t ybase = ((size_t)n * OC_ + og * 32) * (4 * HW_) + (size_t)(2 * h) * 256 + 2 * w;

    for (int oo = 0; oo < 32; oo++) {
        const unsigned short* Go = Gn + (size_t)oo * HW_;
        float b = bo[og * 32 + oo];
        float g[9];
        #pragma unroll
        for (int k = 0; k < 9; k++) {
            float v = bf2f(Go[off[k]]);
            g[k] = val[k] ? v : 0.f;
        }
        float a0 = b, a1 = b, a2 = b, a3 = b;
        #pragma unroll
        for (int k = 0; k < 9; k++) {
            a0 = fmaf(kv[k * 4 + 0], g[k], a0);
            a1 = fmaf(kv[k * 4 + 1], g[k], a1);
            a2 = fmaf(kv[k * 4 + 2], g[k], a2);
            a3 = fmaf(kv[k * 4 + 3], g[k], a3);
        }
        float* yp = y + ybase + (size_t)oo * (4 * HW_);
        float2 r0; r0.x = a0; r0.y = a1;
        float2 r1; r1.x = a2; r1.y = a3;
        *(float2*)yp = r0;
        *(float2*)(yp + 256) = r1;
    }
}

extern "C" void kernel_launch(void* const* d_in, const int* in_sizes, int n_in,
                              void* d_out, int out_size, void* d_ws, size_t ws_size,
                              hipStream_t stream) {
    const float* x  = (const float*)d_in[0];
    const float* wd = (const float*)d_in[1];
    const float* bd = (const float*)d_in[2];
    const float* we = (const float*)d_in[3];
    const float* be = (const float*)d_in[4];
    const float* wo = (const float*)d_in[5];
    const float* bo = (const float*)d_in[6];
    float* y = (float*)d_out;

    float* t    = (float*)d_ws;                        // 4*64*16384 f32   = 16.8 MB
    float* kern = t + (size_t)N_ * CD_ * HW_;          // 65536*36 f32     =  9.4 MB
    short* wob  = (short*)(kern + (size_t)N_ * HW_ * E_);  // 256*256 bf16
    short* G    = wob + (size_t)OC_ * C_;              // 4*256*16384 bf16 = 33.5 MB

    k_prep<<<64,   256, 0, stream>>>(wo, wob);
    k_down<<<256,  512, 0, stream>>>(x, wd, bd, t);
    k_enc <<<1024, 256, 0, stream>>>(t, we, be, kern);
    k_gemm<<<512,  512, 0, stream>>>(x, wob, G);
    k_up  <<<2048, 256, 0, stream>>>(G, kern, bo, y);
}

// Round 5
// 207.714 us; speedup vs baseline: 3.1044x; 1.0835x over previous
//
#include <hip/hip_runtime.h>
#include <hip/hip_bf16.h>
#include <stddef.h>

typedef __attribute__((ext_vector_type(8))) short short8;
typedef __attribute__((ext_vector_type(4))) short short4v;
typedef __attribute__((ext_vector_type(4))) unsigned short ushort4v;
typedef __attribute__((ext_vector_type(4))) float floatx4;

#define N_ 4
#define C_ 256
#define H_ 128
#define W_ 128
#define HW_ (H_*W_)
#define CD_ 64     // C/4
#define E_ 36      // k2*up2
#define OC_ 256

// round-to-nearest-even f32 -> bf16 bits
static __device__ __forceinline__ unsigned short f2bf(float f) {
    union { float f; unsigned u; } v; v.f = f;
    unsigned r = v.u + 0x7fff + ((v.u >> 16) & 1);
    return (unsigned short)(r >> 16);
}
static __device__ __forceinline__ float bf2f(unsigned short s) {
    union { unsigned u; float f; } v; v.u = ((unsigned)s) << 16;
    return v.f;
}

// ---------------- Kernel 0: w_out -> bf16 ----------------
__global__ __launch_bounds__(256) void k_prep(const float* __restrict__ wo,
                                              short* __restrict__ wob) {
    int i = (blockIdx.x * 256 + threadIdx.x) * 4;
    float4 v = *(const float4*)&wo[i];
    short4v s;
    s.x = (short)f2bf(v.x); s.y = (short)f2bf(v.y);
    s.z = (short)f2bf(v.z); s.w = (short)f2bf(v.w);
    *(short4v*)&wob[i] = s;
}

// ---------------- Kernel 1: 1x1 down conv as f32 GEMM ----------------
// grid 512 = n(4) * pxchunk(128 of 128px); 512 thr; tile M=64 x N=128, K=256/32
#define WST 68
#define XST 132
__global__ __launch_bounds__(512) void k_down(
    const float* __restrict__ x, const float* __restrict__ wd,
    const float* __restrict__ bd, float* __restrict__ t)
{
    __shared__ float Wsm[32 * WST];   // [k][o]  8.7 KB
    __shared__ float Xs[32 * XST];    // [k][px] 16.9 KB
    int tid = threadIdx.x;
    int bx = blockIdx.x;
    int n = bx >> 7;
    int px0 = (bx & 127) * 128;
    int mg = tid >> 5;               // 0..15 -> o = mg*4
    int ng = tid & 31;               // px group of 4
    float acc[4][4];
    #pragma unroll
    for (int i = 0; i < 4; i++)
        #pragma unroll
        for (int j = 0; j < 4; j++) acc[i][j] = 0.f;

    for (int c0 = 0; c0 < C_; c0 += 32) {
        {
            int o = tid >> 3, kb = tid & 7;
            float4 wv = *(const float4*)&wd[o * C_ + c0 + kb * 4];
            Wsm[(kb * 4 + 0) * WST + o] = wv.x;
            Wsm[(kb * 4 + 1) * WST + o] = wv.y;
            Wsm[(kb * 4 + 2) * WST + o] = wv.z;
            Wsm[(kb * 4 + 3) * WST + o] = wv.w;
        }
        {
            int c = tid >> 4, pg = tid & 15;
            const float* xp = &x[((size_t)n * C_ + c0 + c) * HW_ + px0 + pg * 8];
            #pragma unroll
            for (int i = 0; i < 2; i++) {
                float4 v = *(const float4*)(xp + i * 4);
                *(float4*)&Xs[c * XST + pg * 8 + i * 4] = v;
            }
        }
        __syncthreads();
        #pragma unroll 4
        for (int k = 0; k < 32; k++) {
            float4 wv = *(const float4*)&Wsm[k * WST + mg * 4];
            float4 xv = *(const float4*)&Xs[k * XST + ng * 4];
            float xs[4] = {xv.x, xv.y, xv.z, xv.w};
            float ws[4] = {wv.x, wv.y, wv.z, wv.w};
            #pragma unroll
            for (int i = 0; i < 4; i++)
                #pragma unroll
                for (int j = 0; j < 4; j++)
                    acc[i][j] = fmaf(ws[i], xs[j], acc[i][j]);
        }
        __syncthreads();
    }
    #pragma unroll
    for (int i = 0; i < 4; i++) {
        int o = mg * 4 + i;
        float b = bd[o];
        float4 r;
        r.x = acc[i][0] + b; r.y = acc[i][1] + b; r.z = acc[i][2] + b; r.w = acc[i][3] + b;
        *(float4*)&t[((size_t)n * CD_ + o) * HW_ + px0 + ng * 4] = r;
    }
}

// ---------------- Kernel 2: 3x3 enc conv + softmax, split by q ----------------
__global__ __launch_bounds__(256) void k_enc(
    const float* __restrict__ t, const float* __restrict__ we,
    const float* __restrict__ be, float* __restrict__ kern)
{
    int q = blockIdx.x >> 8;
    int px = (blockIdx.x & 255) * 256 + threadIdx.x;   // 0..65535
    int n = px >> 14;
    int hw = px & (HW_ - 1);
    int h = hw >> 7, w = hw & (W_ - 1);
    float acc[9];
    #pragma unroll
    for (int k = 0; k < 9; k++) acc[k] = be[k * 4 + q];
    const float* tb = t + (size_t)n * CD_ * HW_;
    bool hv[3], wv[3];
    int ho[3], wo_[3];
    #pragma unroll
    for (int d = 0; d < 3; d++) {
        int hh = h + d - 1; hv[d] = (hh >= 0 && hh < H_); ho[d] = hh * W_;
        int ww = w + d - 1; wv[d] = (ww >= 0 && ww < W_); wo_[d] = ww;
    }
    for (int c = 0; c < CD_; c++) {
        float tv[9];
        #pragma unroll
        for (int di = 0; di < 3; di++)
            #pragma unroll
            for (int dj = 0; dj < 3; dj++)
                tv[di * 3 + dj] = (hv[di] && wv[dj]) ? tb[c * HW_ + ho[di] + wo_[dj]] : 0.f;
        #pragma unroll
        for (int k = 0; k < 9; k++) {
            const float* wp = we + ((size_t)(k * 4 + q) * CD_ + c) * 9;  // uniform -> s_load
            float a = acc[k];
            #pragma unroll
            for (int ij = 0; ij < 9; ij++) a = fmaf(tv[ij], wp[ij], a);
            acc[k] = a;
        }
    }
    float m = acc[0];
    #pragma unroll
    for (int k = 1; k < 9; k++) m = fmaxf(m, acc[k]);
    float ex[9], s = 0.f;
    #pragma unroll
    for (int k = 0; k < 9; k++) { ex[k] = __expf(acc[k] - m); s += ex[k]; }
    float inv = 1.f / s;
    float* kp = kern + (size_t)px * E_ + q;
    #pragma unroll
    for (int k = 0; k < 9; k++) kp[k * 4] = ex[k] * inv;
}

// ---------------- Kernel 3: G = w_out @ x (bf16 MFMA, low-res) ----------------
// grid 512 = n(4) * pxblk(128 of 128 px); 512 thr = 8 waves (2M x 4N)
// G stored as o-quads: [n][64][HW] of ushort4 (4 consecutive o per element)
__global__ __launch_bounds__(512, 4) void k_gemm(
    const float* __restrict__ x, const short* __restrict__ wob,
    unsigned short* __restrict__ Gq)
{
    __shared__ short Asm[2][256 * 40];   // 2 x 20 KB
    __shared__ short Bsm[2][128 * 40];   // 2 x 10 KB

    int tid = threadIdx.x;
    int bx = blockIdx.x;
    int n = bx >> 7;
    int px0 = (bx & 127) * 128;

    int lane = tid & 63;
    int wave = tid >> 6;
    int wm = wave >> 2, wn = wave & 3;

    int ao = tid >> 1, ah = tid & 1;     // A stage role
    int bpx = tid & 127, bcq = tid >> 7; // B stage role (px, 8-ch quarter)

    const float* xb = x + (size_t)n * C_ * HW_ + px0 + bpx;
    const short* wr = wob + ao * C_ + ah * 16;

    short8 a0, a1;
    float xg[8];

    auto issue = [&](int c0) {
        a0 = *(const short8*)(wr + c0);
        a1 = *(const short8*)(wr + c0 + 8);
        #pragma unroll
        for (int j = 0; j < 8; j++)
            xg[j] = xb[(size_t)(c0 + bcq * 8 + j) * HW_];
    };
    auto commit = [&](int buf) {
        short* ad = &Asm[buf][ao * 40 + ah * 16];
        *(short8*)ad = a0;
        *(short8*)(ad + 8) = a1;
        short8 bv;
        #pragma unroll
        for (int j = 0; j < 8; j++) bv[j] = (short)f2bf(xg[j]);
        *(short8*)&Bsm[buf][bpx * 40 + bcq * 8] = bv;
    };

    floatx4 acc[8][2];
    #pragma unroll
    for (int fm = 0; fm < 8; fm++) {
        acc[fm][0] = (floatx4)0.f;
        acc[fm][1] = (floatx4)0.f;
    }

    issue(0);
    commit(0);
    __syncthreads();

    for (int kc = 0; kc < 8; kc++) {
        int cur = kc & 1;
        if (kc < 7) issue((kc + 1) * 32);
        short8 bfrag[2];
        #pragma unroll
        for (int fn = 0; fn < 2; fn++) {
            int col = wn * 32 + fn * 16 + (lane & 15);
            bfrag[fn] = *(const short8*)&Bsm[cur][col * 40 + (lane >> 4) * 8];
        }
        #pragma unroll
        for (int fm = 0; fm < 8; fm++) {
            int row = wm * 128 + fm * 16 + (lane & 15);
            short8 af = *(const short8*)&Asm[cur][row * 40 + (lane >> 4) * 8];
            acc[fm][0] = __builtin_amdgcn_mfma_f32_16x16x32_bf16(af, bfrag[0], acc[fm][0], 0, 0, 0);
            acc[fm][1] = __builtin_amdgcn_mfma_f32_16x16x32_bf16(af, bfrag[1], acc[fm][1], 0, 0, 0);
        }
        if (kc < 7) {
            commit(cur ^ 1);
            __syncthreads();
        }
    }
    // epilogue: D row=(lane>>4)*4+i -> a full o-quad; 8-B coalesced stores
    #pragma unroll
    for (int fm = 0; fm < 8; fm++) {
        int oq = wm * 32 + fm * 4 + (lane >> 4);   // o-quad index
        #pragma unroll
        for (int fn = 0; fn < 2; fn++) {
            int col = px0 + wn * 32 + fn * 16 + (lane & 15);
            ushort4v v;
            v.x = f2bf(acc[fm][fn][0]);
            v.y = f2bf(acc[fm][fn][1]);
            v.z = f2bf(acc[fm][fn][2]);
            v.w = f2bf(acc[fm][fn][3]);
            *(ushort4v*)&Gq[(((size_t)n * 64 + oq) * HW_ + col) * 4] = v;
        }
    }
}

// ---------------- Kernel 4: 9-tap combine + pixel shuffle + bias ----------------
// grid 2048; mapping: bx = (n*64 + og*8 + hbhi)*8 + (hb&7)  -> XCD = hb%8,
// so the 8 og-siblings sharing a kern slice land on the SAME XCD (L2-hot kern).
// 256 thr: (h-half, w); per thread: 8 o-quads x 9 taps (8-B loads).
__global__ __launch_bounds__(256) void k_up(
    const unsigned short* __restrict__ Gq, const float* __restrict__ kern,
    const float* __restrict__ bo, float* __restrict__ y)
{
    int bx = blockIdx.x;
    int x7 = bx & 7;
    int g  = bx >> 3;
    int hbhi = g & 7;
    int og = (g >> 3) & 7;
    int n  = g >> 6;
    int hb = hbhi * 8 + x7;

    int tid = threadIdx.x;
    int h = hb * 2 + (tid >> 7);
    int w = tid & 127;

    // per-pixel kernel weights: 36 f32
    const float* kp = kern + ((size_t)((n * H_ + h) * W_) + w) * E_;
    float kv[36];
    #pragma unroll
    for (int i = 0; i < 9; i++) {
        float4 v = *(const float4*)(kp + i * 4);
        kv[i * 4] = v.x; kv[i * 4 + 1] = v.y; kv[i * 4 + 2] = v.z; kv[i * 4 + 3] = v.w;
    }

    // tap offsets (clamped) + validity
    int off[9]; bool val[9];
    #pragma unroll
    for (int di = 0; di < 3; di++) {
        int hh = h + di - 1;
        bool hvv = (hh >= 0 && hh < H_);
        int hc = hvv ? hh : h;
        #pragma unroll
        for (int dj = 0; dj < 3; dj++) {
            int ww = w + dj - 1;
            bool wvv = (ww >= 0 && ww < W_);
            int wc = wvv ? ww : w;
            off[di * 3 + dj] = hc * W_ + wc;
            val[di * 3 + dj] = hvv && wvv;
        }
    }

    const unsigned short* Gb = Gq + ((size_t)n * 64 + og * 8) * HW_ * 4;
    size_t ybase = ((size_t)n * OC_ + og * 32) * (4 * HW_) + (size_t)(2 * h) * 256 + 2 * w;

    #pragma unroll 2
    for (int j = 0; j < 8; j++) {           // o-quads within og
        const unsigned short* Gj = Gb + (size_t)j * HW_ * 4;
        float b0 = bo[og * 32 + j * 4 + 0];
        float b1 = bo[og * 32 + j * 4 + 1];
        float b2 = bo[og * 32 + j * 4 + 2];
        float b3 = bo[og * 32 + j * 4 + 3];
        float a[4][4];
        #pragma unroll
        for (int s = 0; s < 4; s++) { a[0][s] = b0; a[1][s] = b1; a[2][s] = b2; a[3][s] = b3; }
        #pragma unroll
        for (int k = 0; k < 9; k++) {
            ushort4v gv = *(const ushort4v*)(Gj + (size_t)off[k] * 4);
            float g0 = val[k] ? bf2f(gv.x) : 0.f;
            float g1 = val[k] ? bf2f(gv.y) : 0.f;
            float g2 = val[k] ? bf2f(gv.z) : 0.f;
            float g3 = val[k] ? bf2f(gv.w) : 0.f;
            #pragma unroll
            for (int s = 0; s < 4; s++) {
                float kw = kv[k * 4 + s];
                a[0][s] = fmaf(g0, kw, a[0][s]);
                a[1][s] = fmaf(g1, kw, a[1][s]);
                a[2][s] = fmaf(g2, kw, a[2][s]);
                a[3][s] = fmaf(g3, kw, a[3][s]);
            }
        }
        #pragma unroll
        for (int i = 0; i < 4; i++) {
            float* yp = y + ybase + (size_t)(j * 4 + i) * (4 * HW_);
            float2 r0; r0.x = a[i][0]; r0.y = a[i][1];
            float2 r1; r1.x = a[i][2]; r1.y = a[i][3];
            *(float2*)yp = r0;
            *(float2*)(yp + 256) = r1;
        }
    }
}

extern "C" void kernel_launch(void* const* d_in, const int* in_sizes, int n_in,
                              void* d_out, int out_size, void* d_ws, size_t ws_size,
                              hipStream_t stream) {
    const float* x  = (const float*)d_in[0];
    const float* wd = (const float*)d_in[1];
    const float* bd = (const float*)d_in[2];
    const float* we = (const float*)d_in[3];
    const float* be = (const float*)d_in[4];
    const float* wo = (const float*)d_in[5];
    const float* bo = (const float*)d_in[6];
    float* y = (float*)d_out;

    float* t    = (float*)d_ws;                        // 4*64*16384 f32   = 16.8 MB
    float* kern = t + (size_t)N_ * CD_ * HW_;          // 65536*36 f32     =  9.4 MB
    short* wob  = (short*)(kern + (size_t)N_ * HW_ * E_);  // 256*256 bf16
    unsigned short* Gq = (unsigned short*)(wob + (size_t)OC_ * C_);  // 33.5 MB

    k_prep<<<64,   256, 0, stream>>>(wo, wob);
    k_down<<<512,  512, 0, stream>>>(x, wd, bd, t);
    k_enc <<<1024, 256, 0, stream>>>(t, we, be, kern);
    k_gemm<<<512,  512, 0, stream>>>(x, wob, Gq);
    k_up  <<<2048, 256, 0, stream>>>(Gq, kern, bo, y);
}